// Round 5
// baseline (552.537 us; speedup 1.0000x reference)
//
#include <hip/hip_runtime.h>
#include <hip/hip_bf16.h>

// RecursiveNet bf16-MFMA, round 8: collapse mid-pyramid dispatches.
//   prep(bias+repack) -> pair(0,1) -> tri(2,3,4) -> tri(5,6,7) -> pair(8,9)
//   -> tail(10..17).  8 dispatches -> 6; stage-3/stage-5 global intermediates
//   eliminated (tri keeps them in LDS: bin 264 rows + m1 131 rows + m2
//   overlaying bin = 101 KB, 1 block/CU).
// pair01 verdict stands (r5/r6): random-gather segment-count floor ~158 us.
// tail: r7's 16-wave version (proven -13 us). pair89/pair01 bodies unchanged.

typedef __bf16 v8bf __attribute__((ext_vector_type(8)));
typedef float v16f __attribute__((ext_vector_type(16)));

__device__ __forceinline__ ushort f2bf(float f) {
    __hip_bfloat16 h = __float2bfloat16(f);
    return *reinterpret_cast<ushort*>(&h);
}
__device__ __forceinline__ unsigned pack2(float lo, float hi) {
    return (unsigned)f2bf(lo) | ((unsigned)f2bf(hi) << 16);
}
__device__ __forceinline__ float leaky(float y) { return (y >= 0.f) ? y : 0.2f * y; }

#define ZACC {0.f,0.f,0.f,0.f,0.f,0.f,0.f,0.f,0.f,0.f,0.f,0.f,0.f,0.f,0.f,0.f}

// ---------------------------------------------------------------------------
// prep: blocks 0..17 -> effective bias per depth row; blocks 18..145 -> A repack
__global__ __launch_bounds__(256)
void prep_kernel(const float* __restrict__ W, const float* __restrict__ b,
                 const float* __restrict__ depth, float* __restrict__ Bst,
                 ushort* __restrict__ A) {
    if (blockIdx.x < 18) {
        if (threadIdx.x < 128) {
            int i = blockIdx.x, o = threadIdx.x;
            const float* Wo = W + (size_t)o * 512 + 256;
            const float* di = depth + (size_t)i * 128;
            float s = b[o];
#pragma unroll 8
            for (int c = 0; c < 128; ++c) s += di[c] * (Wo[2 * c] + Wo[2 * c + 1]);
            Bst[i * 128 + o] = s;
        }
    } else {
        int o = blockIdx.x - 18, c = threadIdx.x;
        float v = (c < 128) ? W[(size_t)o * 512 + 2 * c]
                            : W[(size_t)o * 512 + 2 * (c - 128) + 1];
        A[o * 256 + c] = f2bf(v);
    }
}

// ---------------------------------------------------------------------------
#define WAVE_SETUP()                                                          \
    const int tid = threadIdx.x;                                              \
    const int lane = tid & 63;                                                \
    const int w = tid >> 6;                                                   \
    const int n31 = lane & 31;                                                \
    const int h = lane >> 5;                                                  \
    v8bf af[16];                                                              \
    {                                                                         \
        const ushort* Arow = A + (size_t)(w * 32 + n31) * 256 + h * 8;        \
        _Pragma("unroll")                                                     \
        for (int s = 0; s < 16; ++s) af[s] = *(const v8bf*)&Arow[s * 16];     \
    }

#define LOAD_BIAS(dst_, Bs)                                                   \
    float dst_[16];                                                           \
    _Pragma("unroll")                                                         \
    for (int r = 0; r < 16; ++r)                                              \
        dst_[r] = (Bs)[w * 32 + (r & 3) + 8 * (r >> 2) + 4 * h];

// 16 MFMA from a swizzled LDS tile (rows r0_, r1_ local, pre-clamped)
#define MFMA_TILE_LDS(buf, r0_, r1_, acc)                                     \
    {                                                                         \
        const ushort* sp0 = (buf) + (r0_) * 128;                              \
        const ushort* sp1 = (buf) + (r1_) * 128;                              \
        const int mm0 = (r0_) & 15, mm1 = (r1_) & 15;                         \
        _Pragma("unroll")                                                     \
        for (int s = 0; s < 8; ++s)                                           \
            acc = __builtin_amdgcn_mfma_f32_32x32x16_bf16(                    \
                af[s], *(const v8bf*)&sp0[((2 * s + h) ^ mm0) * 8], acc, 0, 0, 0); \
        _Pragma("unroll")                                                     \
        for (int s = 0; s < 8; ++s)                                           \
            acc = __builtin_amdgcn_mfma_f32_32x32x16_bf16(                    \
                af[8 + s], *(const v8bf*)&sp1[((2 * s + h) ^ mm1) * 8], acc, 0, 0, 0); \
    }

// Pooled activation + store of one tile's outputs (writes LDS row u_, swizzled)
#define POOL_STORE_LDS(dstbuf, u_, guard_)                                    \
    _Pragma("unroll")                                                         \
    for (int q = 0; q < 4; ++q) {                                             \
        float pv[4];                                                          \
        _Pragma("unroll")                                                     \
        for (int j = 0; j < 4; ++j) {                                         \
            float y = leaky(acc[4 * q + j] + bias_r[4 * q + j]);              \
            float y2 = __shfl_xor(y, 1, 64);                                  \
            pv[j] = fmaxf(y, y2);                                             \
        }                                                                     \
        if (guard_) {                                                         \
            uint2 v;                                                          \
            v.x = pack2(pv[0], pv[1]);                                        \
            v.y = pack2(pv[2], pv[3]);                                        \
            *(uint2*)&(dstbuf)[(u_) * 128 + (((4 * w + q) ^ ((u_) & 15)) * 8) + 4 * h] = v; \
        }                                                                     \
    }

// ---------------------------------------------------------------------------
// Fused pair of stages. Block -> 32 outputs of the second stage.
__global__ __launch_bounds__(256)
void pair_fused(const ushort* __restrict__ Xin,   // bf16 [Lin][128] (stage>0)
                const float* __restrict__ x0,     // fp32 [N][128]  (first pair)
                const int* __restrict__ perm,     // [N]            (first pair)
                const ushort* __restrict__ A,     // bf16 [128][256]
                const float* __restrict__ Bst2,   // fp32 [2][128]
                ushort* __restrict__ Y,           // bf16 [Lp2][128]
                int Lin, int Lp2, int stage0) {
    __shared__ __align__(16) ushort xin[132 * 128];  // 33 KB
    __shared__ __align__(16) ushort mid[65 * 128];   // 16.6 KB
    __shared__ int prow[132];

    const int U = blockIdx.x * 32;
    const int t0 = U * 4;

    if (stage0) {
        for (int r = threadIdx.x; r < 132; r += 256)
            prow[r] = perm[min(t0 + r, Lin - 1)];
        __syncthreads();
    }
    for (int idx = threadIdx.x; idx < 132 * 16; idx += 256) {
        int row = idx >> 4, ck = idx & 15;
        int t = min(t0 + row, Lin - 1);
        int dst = row * 128 + ((ck ^ (row & 15)) * 8);
        if (stage0) {
            const float* s = x0 + (size_t)prow[row] * 128 + ck * 8;
            float4 a = *(const float4*)s;
            float4 bq = *(const float4*)(s + 4);
            uint4 v;
            v.x = pack2(a.x, a.y);  v.y = pack2(a.z, a.w);
            v.z = pack2(bq.x, bq.y); v.w = pack2(bq.z, bq.w);
            *(uint4*)&xin[dst] = v;
        } else {
            *(uint4*)&xin[dst] = *(const uint4*)&Xin[(size_t)t * 128 + ck * 8];
        }
    }
    __syncthreads();

    WAVE_SETUP();

    // ---- stage A: 5 tiles -> mid (LDS)
    {
        LOAD_BIAS(bias_r, Bst2);
#pragma unroll
        for (int ti = 0; ti < 5; ++ti) {
            const int p = 32 * ti + n31;
            const int r0 = min(p, 131), r1 = min(p + 1, 131);
            v16f acc = ZACC;
            MFMA_TILE_LDS(xin, r0, r1, acc);
            const int u1 = 16 * ti + (n31 >> 1);
            const bool act = !(lane & 1) && (u1 < 65);
            POOL_STORE_LDS(mid, u1, act);
        }
    }
    __syncthreads();

    // ---- stage B: 2 tiles -> global
    {
        LOAD_BIAS(bias_r, Bst2 + 128);
#pragma unroll
        for (int ti = 0; ti < 2; ++ti) {
            const int p = 32 * ti + n31;
            v16f acc = ZACC;
            MFMA_TILE_LDS(mid, p, p + 1, acc);
            const int u2 = U + 16 * ti + (n31 >> 1);
            const bool act = !(lane & 1) && (u2 < Lp2);
#pragma unroll
            for (int q = 0; q < 4; ++q) {
                float pv[4];
#pragma unroll
                for (int j = 0; j < 4; ++j) {
                    float y = leaky(acc[4 * q + j] + bias_r[4 * q + j]);
                    float y2 = __shfl_xor(y, 1, 64);
                    pv[j] = fmaxf(y, y2);
                }
                if (act) {
                    uint2 v;
                    v.x = pack2(pv[0], pv[1]);
                    v.y = pack2(pv[2], pv[3]);
                    *(uint2*)&Y[(size_t)u2 * 128 + w * 32 + 8 * q + 4 * h] = v;
                }
            }
        }
    }
}

// ---------------------------------------------------------------------------
// Fused TRIPLE of stages. Block -> 32 outputs of the third stage.
//   input rows [8U, 8U+263) staged (264 rows, clamped)   bin: 67.6 KB
//   stage A: 9 tiles -> m1 (131 rows, 33.5 KB)
//   stage B: 5 tiles -> m2 (65 rows, overlays bin)
//   stage C: 2 tiles -> global
__global__ __launch_bounds__(256)
void tri_fused(const ushort* __restrict__ Xin,   // bf16 [Lin][128]
               const ushort* __restrict__ A,     // bf16 [128][256]
               const float* __restrict__ Bst3,   // fp32 [3][128]
               ushort* __restrict__ Y,           // bf16 [Lp3][128]
               int Lin, int Lp3) {
    __shared__ __align__(16) ushort bin[264 * 128];  // 67.6 KB (reused as m2)
    __shared__ __align__(16) ushort m1[131 * 128];   // 33.5 KB

    const int U = blockIdx.x * 32;
    const int t0 = U * 8;

    for (int idx = threadIdx.x; idx < 264 * 16; idx += 256) {
        int row = idx >> 4, ck = idx & 15;
        int t = min(t0 + row, Lin - 1);
        *(uint4*)&bin[row * 128 + ((ck ^ (row & 15)) * 8)] =
            *(const uint4*)&Xin[(size_t)t * 128 + ck * 8];
    }
    __syncthreads();

    WAVE_SETUP();

    // ---- stage A: 9 tiles bin(264) -> m1(131)
    {
        LOAD_BIAS(bias_r, Bst3);
#pragma unroll
        for (int ti = 0; ti < 9; ++ti) {
            const int p = 32 * ti + n31;
            const int r0 = min(p, 263), r1 = min(p + 1, 263);
            v16f acc = ZACC;
            MFMA_TILE_LDS(bin, r0, r1, acc);
            const int u1 = 16 * ti + (n31 >> 1);
            const bool act = !(lane & 1) && (u1 < 131);
            POOL_STORE_LDS(m1, u1, act);
        }
    }
    __syncthreads();

    // ---- stage B: 5 tiles m1(131) -> m2(65) [m2 overlays bin]
    ushort* m2 = bin;
    {
        LOAD_BIAS(bias_r, Bst3 + 128);
#pragma unroll
        for (int ti = 0; ti < 5; ++ti) {
            const int p = 32 * ti + n31;
            const int r0 = min(p, 130), r1 = min(p + 1, 130);
            v16f acc = ZACC;
            MFMA_TILE_LDS(m1, r0, r1, acc);
            const int u2 = 16 * ti + (n31 >> 1);
            const bool act = !(lane & 1) && (u2 < 65);
            POOL_STORE_LDS(m2, u2, act);
        }
    }
    __syncthreads();

    // ---- stage C: 2 tiles m2(65) -> global
    {
        LOAD_BIAS(bias_r, Bst3 + 256);
#pragma unroll
        for (int ti = 0; ti < 2; ++ti) {
            const int p = 32 * ti + n31;   // p<=63, p+1<=64 < 65: no clamp
            v16f acc = ZACC;
            MFMA_TILE_LDS(m2, p, p + 1, acc);
            const int u3 = U + 16 * ti + (n31 >> 1);
            const bool act = !(lane & 1) && (u3 < Lp3);
#pragma unroll
            for (int q = 0; q < 4; ++q) {
                float pv[4];
#pragma unroll
                for (int j = 0; j < 4; ++j) {
                    float y = leaky(acc[4 * q + j] + bias_r[4 * q + j]);
                    float y2 = __shfl_xor(y, 1, 64);
                    pv[j] = fmaxf(y, y2);
                }
                if (act) {
                    uint2 v;
                    v.x = pack2(pv[0], pv[1]);
                    v.y = pack2(pv[2], pv[3]);
                    *(uint2*)&Y[(size_t)u3 * 128 + w * 32 + 8 * q + 4 * h] = v;
                }
            }
        }
    }
}

// ---------------------------------------------------------------------------
// Stages 10..17 fused (Lin = 511 -> 1), one block, 16 waves, LDS ping-pong.
__global__ __launch_bounds__(1024)
void tail_fused(const ushort* __restrict__ Xg, const ushort* __restrict__ A,
                const float* __restrict__ BstAll, float* __restrict__ out) {
    extern __shared__ __align__(16) ushort tbuf[];
    ushort* buf0 = tbuf;              // 255 rows
    ushort* buf1 = tbuf + 255 * 128;  // 127 rows

    const int tid = threadIdx.x;
    const int lane = tid & 63;
    const int wv = tid >> 6;          // 0..15
    const int w = wv & 3;             // channel quad
    const int wp = wv >> 2;           // tile parity 0..3
    const int n31 = lane & 31;
    const int h = lane >> 5;
    v8bf af[16];
    {
        const ushort* Arow = A + (size_t)(w * 32 + n31) * 256 + h * 8;
#pragma unroll
        for (int s = 0; s < 16; ++s) af[s] = *(const v8bf*)&Arow[s * 16];
    }

    int Lin = 511;
    for (int st = 0; st < 8; ++st) {
        const int Lp = (Lin - 1) >> 1;
        LOAD_BIAS(bias_r, BstAll + (size_t)(10 + st) * 128);
        ushort* dst = (st & 1) ? buf1 : buf0;
        const ushort* src = (st & 1) ? buf0 : buf1;  // unused for st==0
        const int ntiles = (Lin - 1 + 31) >> 5;
        for (int ti = wp; ti < ntiles; ti += 4) {
            const int t = ti * 32 + n31;
            const int r0 = min(t, Lin - 1), r1 = min(t + 1, Lin - 1);
            v16f acc = ZACC;
            if (st == 0) {
                const ushort* p0 = Xg + (size_t)r0 * 128 + h * 8;
                const ushort* p1 = Xg + (size_t)r1 * 128 + h * 8;
#pragma unroll
                for (int s = 0; s < 8; ++s)
                    acc = __builtin_amdgcn_mfma_f32_32x32x16_bf16(
                        af[s], *(const v8bf*)&p0[s * 16], acc, 0, 0, 0);
#pragma unroll
                for (int s = 0; s < 8; ++s)
                    acc = __builtin_amdgcn_mfma_f32_32x32x16_bf16(
                        af[8 + s], *(const v8bf*)&p1[s * 16], acc, 0, 0, 0);
            } else {
                MFMA_TILE_LDS(src, r0, r1, acc);
            }
            const int u = t >> 1;
            const bool act = !(lane & 1) && (u < Lp);
#pragma unroll
            for (int q = 0; q < 4; ++q) {
                float pv[4];
#pragma unroll
                for (int j = 0; j < 4; ++j) {
                    float y = leaky(acc[4 * q + j] + bias_r[4 * q + j]);
                    float y2 = __shfl_xor(y, 1, 64);
                    pv[j] = fmaxf(y, y2);
                }
                if (act) {
                    if (st < 7) {
                        uint2 v;
                        v.x = pack2(pv[0], pv[1]);
                        v.y = pack2(pv[2], pv[3]);
                        *(uint2*)&dst[u * 128 + (((4 * w + q) ^ (u & 15)) * 8) + 4 * h] = v;
                    } else {
                        float4 o = {pv[0], pv[1], pv[2], pv[3]};
                        *(float4*)&out[w * 32 + 8 * q + 4 * h] = o;
                    }
                }
            }
        }
        __syncthreads();
        Lin = Lp;
    }
}

// ---------------------------------------------------------------------------
extern "C" void kernel_launch(void* const* d_in, const int* in_sizes, int n_in,
                              void* d_out, int out_size, void* d_ws, size_t ws_size,
                              hipStream_t stream) {
    const float* x     = (const float*)d_in[0];   // [524288][128]
    const float* depth = (const float*)d_in[1];   // [32][128]
    const float* W     = (const float*)d_in[2];   // [128][256][2]
    const float* b     = (const float*)d_in[3];   // [128]
    const int*   perm  = (const int*)d_in[4];     // [524288]
    float* out = (float*)d_out;                   // [1][128] fp32

    char* ws = (char*)d_ws;
    float*  Bst = (float*)ws;                                            // 18*128 fp32
    ushort* A   = (ushort*)(ws + 16384);                                 // 128*256 bf16
    ushort* R0  = (ushort*)(ws + 16384 + 65536);                         // 131071 rows max
    ushort* R1  = (ushort*)(ws + 16384 + 65536 + (size_t)131071 * 256);  // 32767 rows max

    prep_kernel<<<146, 256, 0, stream>>>(W, b, depth, Bst, A);

    // (0,1): 524288 -> 131071
    pair_fused<<<4096, 256, 0, stream>>>(nullptr, x, perm, A, Bst, R0,
                                         524288, 131071, 1);
    // (2,3,4): 131071 -> 16383
    tri_fused<<<512, 256, 0, stream>>>(R0, A, Bst + 2 * 128, R1, 131071, 16383);
    // (5,6,7): 16383 -> 2047
    tri_fused<<<64, 256, 0, stream>>>(R1, A, Bst + 5 * 128, R0, 16383, 2047);
    // (8,9): 2047 -> 511
    pair_fused<<<16, 256, 0, stream>>>(R0, nullptr, nullptr, A, Bst + 8 * 128, R1,
                                       2047, 511, 0);
    // 10..17: 511 -> 1
    tail_fused<<<1, 1024, (255 + 127) * 128 * 2, stream>>>(R1, A, Bst, out);
}

// Round 6
// 540.845 us; speedup vs baseline: 1.0216x; 1.0216x over previous
//
#include <hip/hip_runtime.h>
#include <hip/hip_bf16.h>

// RecursiveNet bf16-MFMA, round 9: revert to r7 pipeline (best measured,
// 543.5 us), keep r8's merged prep_kernel only.
//   prep -> pair(0,1) -> pair(2,3) -> pair(4,5) -> pair(6,7) -> pair(8,9)
//   -> tail(10..17, 16 waves).
// Established floors (twice-confirmed nulls):
//   - pair01 ~158 us: random-gather SEGMENT-COUNT bound (r5: concurrency
//     null; r6: bytes/L3 null). 524288 random segments is invariant.
//   - fills ~318 us/iter: harness re-poison at 84% HBM peak, untouchable.
//   - r8: dispatch merging (tri_fused, 101 KB LDS) regressed +9 us ->
//     launch gaps are small; occupancy matters more. Reverted.

typedef __bf16 v8bf __attribute__((ext_vector_type(8)));
typedef float v16f __attribute__((ext_vector_type(16)));

__device__ __forceinline__ ushort f2bf(float f) {
    __hip_bfloat16 h = __float2bfloat16(f);
    return *reinterpret_cast<ushort*>(&h);
}
__device__ __forceinline__ unsigned pack2(float lo, float hi) {
    return (unsigned)f2bf(lo) | ((unsigned)f2bf(hi) << 16);
}
__device__ __forceinline__ float leaky(float y) { return (y >= 0.f) ? y : 0.2f * y; }

#define ZACC {0.f,0.f,0.f,0.f,0.f,0.f,0.f,0.f,0.f,0.f,0.f,0.f,0.f,0.f,0.f,0.f}

// ---------------------------------------------------------------------------
// prep: blocks 0..17 -> effective bias per depth row; blocks 18..145 -> A repack
__global__ __launch_bounds__(256)
void prep_kernel(const float* __restrict__ W, const float* __restrict__ b,
                 const float* __restrict__ depth, float* __restrict__ Bst,
                 ushort* __restrict__ A) {
    if (blockIdx.x < 18) {
        if (threadIdx.x < 128) {
            int i = blockIdx.x, o = threadIdx.x;
            const float* Wo = W + (size_t)o * 512 + 256;
            const float* di = depth + (size_t)i * 128;
            float s = b[o];
#pragma unroll 8
            for (int c = 0; c < 128; ++c) s += di[c] * (Wo[2 * c] + Wo[2 * c + 1]);
            Bst[i * 128 + o] = s;
        }
    } else {
        int o = blockIdx.x - 18, c = threadIdx.x;
        float v = (c < 128) ? W[(size_t)o * 512 + 2 * c]
                            : W[(size_t)o * 512 + 2 * (c - 128) + 1];
        A[o * 256 + c] = f2bf(v);
    }
}

// ---------------------------------------------------------------------------
#define WAVE_SETUP()                                                          \
    const int tid = threadIdx.x;                                              \
    const int lane = tid & 63;                                                \
    const int w = tid >> 6;                                                   \
    const int n31 = lane & 31;                                                \
    const int h = lane >> 5;                                                  \
    v8bf af[16];                                                              \
    {                                                                         \
        const ushort* Arow = A + (size_t)(w * 32 + n31) * 256 + h * 8;        \
        _Pragma("unroll")                                                     \
        for (int s = 0; s < 16; ++s) af[s] = *(const v8bf*)&Arow[s * 16];     \
    }

#define LOAD_BIAS(dst_, Bs)                                                   \
    float dst_[16];                                                           \
    _Pragma("unroll")                                                         \
    for (int r = 0; r < 16; ++r)                                              \
        dst_[r] = (Bs)[w * 32 + (r & 3) + 8 * (r >> 2) + 4 * h];

// 16 MFMA from a swizzled LDS tile (rows r0_, r1_ local, pre-clamped)
#define MFMA_TILE_LDS(buf, r0_, r1_, acc)                                     \
    {                                                                         \
        const ushort* sp0 = (buf) + (r0_) * 128;                              \
        const ushort* sp1 = (buf) + (r1_) * 128;                              \
        const int mm0 = (r0_) & 15, mm1 = (r1_) & 15;                         \
        _Pragma("unroll")                                                     \
        for (int s = 0; s < 8; ++s)                                           \
            acc = __builtin_amdgcn_mfma_f32_32x32x16_bf16(                    \
                af[s], *(const v8bf*)&sp0[((2 * s + h) ^ mm0) * 8], acc, 0, 0, 0); \
        _Pragma("unroll")                                                     \
        for (int s = 0; s < 8; ++s)                                           \
            acc = __builtin_amdgcn_mfma_f32_32x32x16_bf16(                    \
                af[8 + s], *(const v8bf*)&sp1[((2 * s + h) ^ mm1) * 8], acc, 0, 0, 0); \
    }

// ---------------------------------------------------------------------------
// Fused pair of stages. Block -> 32 outputs of the second stage.
__global__ __launch_bounds__(256)
void pair_fused(const ushort* __restrict__ Xin,   // bf16 [Lin][128] (stage>0)
                const float* __restrict__ x0,     // fp32 [N][128]  (first pair)
                const int* __restrict__ perm,     // [N]            (first pair)
                const ushort* __restrict__ A,     // bf16 [128][256]
                const float* __restrict__ Bst2,   // fp32 [2][128]
                ushort* __restrict__ Y,           // bf16 [Lp2][128]
                int Lin, int Lp2, int stage0) {
    __shared__ __align__(16) ushort xin[132 * 128];  // 33 KB
    __shared__ __align__(16) ushort mid[65 * 128];   // 16.6 KB
    __shared__ int prow[132];

    const int U = blockIdx.x * 32;
    const int t0 = U * 4;

    if (stage0) {
        for (int r = threadIdx.x; r < 132; r += 256)
            prow[r] = perm[min(t0 + r, Lin - 1)];
        __syncthreads();
    }
    for (int idx = threadIdx.x; idx < 132 * 16; idx += 256) {
        int row = idx >> 4, ck = idx & 15;
        int t = min(t0 + row, Lin - 1);
        int dst = row * 128 + ((ck ^ (row & 15)) * 8);
        if (stage0) {
            const float* s = x0 + (size_t)prow[row] * 128 + ck * 8;
            float4 a = *(const float4*)s;
            float4 bq = *(const float4*)(s + 4);
            uint4 v;
            v.x = pack2(a.x, a.y);  v.y = pack2(a.z, a.w);
            v.z = pack2(bq.x, bq.y); v.w = pack2(bq.z, bq.w);
            *(uint4*)&xin[dst] = v;
        } else {
            *(uint4*)&xin[dst] = *(const uint4*)&Xin[(size_t)t * 128 + ck * 8];
        }
    }
    __syncthreads();

    WAVE_SETUP();

    // ---- stage A: 5 tiles -> mid (LDS)
    {
        LOAD_BIAS(bias_r, Bst2);
#pragma unroll
        for (int ti = 0; ti < 5; ++ti) {
            const int p = 32 * ti + n31;
            const int r0 = min(p, 131), r1 = min(p + 1, 131);
            v16f acc = ZACC;
            MFMA_TILE_LDS(xin, r0, r1, acc);
            const int u1 = 16 * ti + (n31 >> 1);
            const bool act = !(lane & 1) && (u1 < 65);
#pragma unroll
            for (int q = 0; q < 4; ++q) {
                float pv[4];
#pragma unroll
                for (int j = 0; j < 4; ++j) {
                    float y = leaky(acc[4 * q + j] + bias_r[4 * q + j]);
                    float y2 = __shfl_xor(y, 1, 64);
                    pv[j] = fmaxf(y, y2);
                }
                if (act) {
                    uint2 v;
                    v.x = pack2(pv[0], pv[1]);
                    v.y = pack2(pv[2], pv[3]);
                    *(uint2*)&mid[u1 * 128 + (((4 * w + q) ^ (u1 & 15)) * 8) + 4 * h] = v;
                }
            }
        }
    }
    __syncthreads();

    // ---- stage B: 2 tiles -> global
    {
        LOAD_BIAS(bias_r, Bst2 + 128);
#pragma unroll
        for (int ti = 0; ti < 2; ++ti) {
            const int p = 32 * ti + n31;
            v16f acc = ZACC;
            MFMA_TILE_LDS(mid, p, p + 1, acc);
            const int u2 = U + 16 * ti + (n31 >> 1);
            const bool act = !(lane & 1) && (u2 < Lp2);
#pragma unroll
            for (int q = 0; q < 4; ++q) {
                float pv[4];
#pragma unroll
                for (int j = 0; j < 4; ++j) {
                    float y = leaky(acc[4 * q + j] + bias_r[4 * q + j]);
                    float y2 = __shfl_xor(y, 1, 64);
                    pv[j] = fmaxf(y, y2);
                }
                if (act) {
                    uint2 v;
                    v.x = pack2(pv[0], pv[1]);
                    v.y = pack2(pv[2], pv[3]);
                    *(uint2*)&Y[(size_t)u2 * 128 + w * 32 + 8 * q + 4 * h] = v;
                }
            }
        }
    }
}

// ---------------------------------------------------------------------------
// Stages 10..17 fused (Lin = 511 -> 1), one block, 16 waves, LDS ping-pong.
// w  = wave&3 : channel quad (which 32 output channels / A rows)
// wp = wave>>2: tile parity  (tiles ti = wp, wp+4, ...)
__global__ __launch_bounds__(1024)
void tail_fused(const ushort* __restrict__ Xg, const ushort* __restrict__ A,
                const float* __restrict__ BstAll, float* __restrict__ out) {
    extern __shared__ __align__(16) ushort tbuf[];
    ushort* buf0 = tbuf;              // 255 rows
    ushort* buf1 = tbuf + 255 * 128;  // 127 rows

    const int tid = threadIdx.x;
    const int lane = tid & 63;
    const int wv = tid >> 6;          // 0..15
    const int w = wv & 3;             // channel quad
    const int wp = wv >> 2;           // tile parity 0..3
    const int n31 = lane & 31;
    const int h = lane >> 5;
    v8bf af[16];
    {
        const ushort* Arow = A + (size_t)(w * 32 + n31) * 256 + h * 8;
#pragma unroll
        for (int s = 0; s < 16; ++s) af[s] = *(const v8bf*)&Arow[s * 16];
    }

    int Lin = 511;
    for (int st = 0; st < 8; ++st) {
        const int Lp = (Lin - 1) >> 1;
        LOAD_BIAS(bias_r, BstAll + (size_t)(10 + st) * 128);
        ushort* dst = (st & 1) ? buf1 : buf0;
        const ushort* src = (st & 1) ? buf0 : buf1;  // unused for st==0
        const int ntiles = (Lin - 1 + 31) >> 5;
        for (int ti = wp; ti < ntiles; ti += 4) {
            const int t = ti * 32 + n31;
            const int r0 = min(t, Lin - 1), r1 = min(t + 1, Lin - 1);
            v16f acc = ZACC;
            if (st == 0) {
                const ushort* p0 = Xg + (size_t)r0 * 128 + h * 8;
                const ushort* p1 = Xg + (size_t)r1 * 128 + h * 8;
#pragma unroll
                for (int s = 0; s < 8; ++s)
                    acc = __builtin_amdgcn_mfma_f32_32x32x16_bf16(
                        af[s], *(const v8bf*)&p0[s * 16], acc, 0, 0, 0);
#pragma unroll
                for (int s = 0; s < 8; ++s)
                    acc = __builtin_amdgcn_mfma_f32_32x32x16_bf16(
                        af[8 + s], *(const v8bf*)&p1[s * 16], acc, 0, 0, 0);
            } else {
                MFMA_TILE_LDS(src, r0, r1, acc);
            }
            const int u = t >> 1;
            const bool act = !(lane & 1) && (u < Lp);
#pragma unroll
            for (int q = 0; q < 4; ++q) {
                float pv[4];
#pragma unroll
                for (int j = 0; j < 4; ++j) {
                    float y = leaky(acc[4 * q + j] + bias_r[4 * q + j]);
                    float y2 = __shfl_xor(y, 1, 64);
                    pv[j] = fmaxf(y, y2);
                }
                if (act) {
                    if (st < 7) {
                        uint2 v;
                        v.x = pack2(pv[0], pv[1]);
                        v.y = pack2(pv[2], pv[3]);
                        *(uint2*)&dst[u * 128 + (((4 * w + q) ^ (u & 15)) * 8) + 4 * h] = v;
                    } else {
                        float4 o = {pv[0], pv[1], pv[2], pv[3]};
                        *(float4*)&out[w * 32 + 8 * q + 4 * h] = o;
                    }
                }
            }
        }
        __syncthreads();
        Lin = Lp;
    }
}

// ---------------------------------------------------------------------------
extern "C" void kernel_launch(void* const* d_in, const int* in_sizes, int n_in,
                              void* d_out, int out_size, void* d_ws, size_t ws_size,
                              hipStream_t stream) {
    const float* x     = (const float*)d_in[0];   // [524288][128]
    const float* depth = (const float*)d_in[1];   // [32][128]
    const float* W     = (const float*)d_in[2];   // [128][256][2]
    const float* b     = (const float*)d_in[3];   // [128]
    const int*   perm  = (const int*)d_in[4];     // [524288]
    float* out = (float*)d_out;                   // [1][128] fp32

    char* ws = (char*)d_ws;
    float*  Bst = (float*)ws;                                            // 18*128 fp32
    ushort* A   = (ushort*)(ws + 16384);                                 // 128*256 bf16
    ushort* R0  = (ushort*)(ws + 16384 + 65536);                         // 131071 rows max
    ushort* R1  = (ushort*)(ws + 16384 + 65536 + (size_t)131071 * 256);  // 32767 rows max

    prep_kernel<<<146, 256, 0, stream>>>(W, b, depth, Bst, A);

    // (0,1): 524288 -> 131071
    pair_fused<<<4096, 256, 0, stream>>>(nullptr, x, perm, A, Bst, R0,
                                         524288, 131071, 1);
    // (2,3): 131071 -> 32767
    pair_fused<<<1024, 256, 0, stream>>>(R0, nullptr, nullptr, A, Bst + 2 * 128, R1,
                                         131071, 32767, 0);
    // (4,5): 32767 -> 8191
    pair_fused<<<256, 256, 0, stream>>>(R1, nullptr, nullptr, A, Bst + 4 * 128, R0,
                                        32767, 8191, 0);
    // (6,7): 8191 -> 2047
    pair_fused<<<64, 256, 0, stream>>>(R0, nullptr, nullptr, A, Bst + 6 * 128, R1,
                                       8191, 2047, 0);
    // (8,9): 2047 -> 511
    pair_fused<<<16, 256, 0, stream>>>(R1, nullptr, nullptr, A, Bst + 8 * 128, R0,
                                       2047, 511, 0);
    // 10..17: 511 -> 1
    tail_fused<<<1, 1024, (255 + 127) * 128 * 2, stream>>>(R0, A, Bst, out);
}